// Round 1
// baseline (1654.835 us; speedup 1.0000x reference)
//
#include <hip/hip_runtime.h>
#include <math.h>

#define N_NODES 128
#define IN_DIM  512
#define MEM     256
#define HID     128
#define NCLS    5
#define G       16

// ws layout (float offsets)
#define IOUX_OFF 0                      // 2 * 128 * 768
#define FX_OFF   196608                 // 2 * 129 * 256 (row 128 = zero sentinel)
#define H_OFF    262656                 // 2 * 128 * 256
#define FC_OFF   328192                 // 2 * 128 * 256
// total floats: 393728  (~1.5 MB)

__device__ __forceinline__ float sigmf(float x) {
    return 1.0f / (1.0f + __expf(-x));
}
__device__ __forceinline__ float tanh_fast(float x) {
    float e = __expf(2.0f * x);
    return 1.0f - 2.0f / (e + 1.0f);
}

// ---------------------------------------------------------------------------
// K1: per (tree,node): gather emb row, compute ioux = X@Wioux + bioux (768)
// and fx = X@Wfx + bfx (256). 256 blocks (2 trees * 128 nodes), 256 threads.
// ---------------------------------------------------------------------------
__global__ __launch_bounds__(256) void k1_prep(
        const float* __restrict__ emb,
        const float* __restrict__ Wioux, const float* __restrict__ bioux,
        const float* __restrict__ Wfx,   const float* __restrict__ bfx,
        const int* __restrict__ linputs, const int* __restrict__ rinputs,
        float* __restrict__ ws) {
    int tree = blockIdx.x >> 7;
    int node = blockIdx.x & 127;
    const int* inp = tree ? rinputs : linputs;
    int tok = inp[node];

    __shared__ float X[IN_DIM];
    int tid = threadIdx.x;
    for (int i = tid; i < IN_DIM; i += 256)
        X[i] = emb[(size_t)tok * IN_DIM + i];
    __syncthreads();

    float a0 = 0.f, a1 = 0.f, a2 = 0.f, a3 = 0.f;
    for (int k = 0; k < IN_DIM; k++) {
        float x = X[k];
        a0 = fmaf(x, Wioux[k * 768 + tid],        a0);
        a1 = fmaf(x, Wioux[k * 768 + 256 + tid],  a1);
        a2 = fmaf(x, Wioux[k * 768 + 512 + tid],  a2);
        a3 = fmaf(x, Wfx[k * 256 + tid],          a3);
    }
    float* ioux = ws + IOUX_OFF + (size_t)(tree * 128 + node) * 768;
    ioux[tid]       = a0 + bioux[tid];
    ioux[256 + tid] = a1 + bioux[256 + tid];
    ioux[512 + tid] = a2 + bioux[512 + tid];
    float* fx = ws + FX_OFF + ((size_t)tree * 129 + node) * 256;
    fx[tid] = a3 + bfx[tid];
    if (node == 0) {   // zero the sentinel fx row (parent == 128)
        float* fx128 = ws + FX_OFF + ((size_t)tree * 129 + 128) * 256;
        fx128[tid] = 0.f;
    }
}

// ---------------------------------------------------------------------------
// K2: level-order TreeLSTM scan. 1 block per tree, 1024 threads.
// Gather formulation: hsin[t] = sum_{children} H[c], fcin[t] = sum FC[c].
// ---------------------------------------------------------------------------
__global__ __launch_bounds__(1024) void k2_scan(
        const float* __restrict__ Wiouh, const float* __restrict__ biouh,
        const float* __restrict__ Wfh,   const float* __restrict__ bfh,
        const int* __restrict__ lparents, const int* __restrict__ rparents,
        float* __restrict__ ws) {
    int tree = blockIdx.x;
    const int* parents = tree ? rparents : lparents;
    const float* ioux = ws + IOUX_OFF + (size_t)tree * 128 * 768;
    const float* fx   = ws + FX_OFF   + (size_t)tree * 129 * 256;
    float* H  = ws + H_OFF  + (size_t)tree * 128 * 256;
    float* FC = ws + FC_OFF + (size_t)tree * 128 * 256;

    __shared__ float hsin[G][MEM];
    __shared__ float fcin[G][MEM];
    __shared__ float hlds[G][MEM];
    __shared__ int par[N_NODES];
    __shared__ int rnd[N_NODES];
    __shared__ int order[N_NODES];
    __shared__ int rstart[N_NODES + 1];
    __shared__ int kids[N_NODES];
    __shared__ int kstart[N_NODES + 1];
    __shared__ int cnt[N_NODES + 1];
    __shared__ int changed;
    __shared__ int nrounds_s;

    int tid = threadIdx.x;
    int j  = tid & 255;     // column within MEM
    int gh = tid >> 8;      // node-slice 0..3 (4 nodes each)

    // ---- prologue: levels (longest path from leaves) via relaxation ----
    if (tid < N_NODES) { par[tid] = parents[tid]; rnd[tid] = 0; }
    __syncthreads();
    while (true) {
        if (tid == 0) changed = 0;
        __syncthreads();
        if (tid < N_NODES) {
            int p = par[tid];
            if (p < N_NODES) {
                int v = rnd[tid] + 1;
                int old = atomicMax(&rnd[p], v);
                if (old < v) changed = 1;
            }
        }
        __syncthreads();
        int done = (changed == 0);
        __syncthreads();
        if (done) break;
    }
    // ---- counting sort nodes by round (stable) ----
    if (tid <= N_NODES) cnt[tid] = 0;
    __syncthreads();
    if (tid < N_NODES) atomicAdd(&cnt[rnd[tid]], 1);
    __syncthreads();
    if (tid == 0) {
        int acc = 0, mr = 0;
        for (int rr = 0; rr < N_NODES; rr++) {
            rstart[rr] = acc; acc += cnt[rr];
            if (cnt[rr] > 0) mr = rr;
        }
        rstart[N_NODES] = acc;
        nrounds_s = mr + 1;
    }
    __syncthreads();
    if (tid < N_NODES) {
        int rr = rnd[tid]; int rank = 0;
        for (int t2 = 0; t2 < tid; t2++) rank += (rnd[t2] == rr) ? 1 : 0;
        order[rstart[rr] + rank] = tid;
    }
    // ---- children adjacency (stable counting sort by parent) ----
    if (tid <= N_NODES) cnt[tid] = 0;
    __syncthreads();
    if (tid < N_NODES) atomicAdd(&cnt[par[tid]], 1);
    __syncthreads();
    if (tid == 0) {
        int acc = 0;
        for (int t = 0; t <= N_NODES; t++) { kstart[t] = acc; acc += cnt[t]; }
    }
    __syncthreads();
    if (tid < N_NODES) {
        int p = par[tid]; int rank = 0;
        for (int t2 = 0; t2 < tid; t2++) rank += (par[t2] == p) ? 1 : 0;
        kids[kstart[p] + rank] = tid;
    }
    __syncthreads();

    // ---- main level loop ----
    int nr = nrounds_s;
    for (int r = 0; r < nr; r++) {
        int rs = rstart[r], re = rstart[r + 1];
        for (int g0 = 0; g0 < re - rs; g0 += G) {
            int nn = re - rs - g0; if (nn > G) nn = G;

            // stage: gather child sums into hsin/fcin
            for (int i = tid; i < G * MEM; i += 1024) {
                int g = i >> 8, k = i & 255;
                float hs = 0.f, fc = 0.f;
                if (g < nn) {
                    int t = order[rs + g0 + g];
                    for (int ci = kstart[t]; ci < kstart[t + 1]; ci++) {
                        int ch = kids[ci];
                        hs += H[ch * MEM + k];
                        fc += FC[ch * MEM + k];
                    }
                }
                hsin[g][k] = hs; fcin[g][k] = fc;
            }
            __syncthreads();

            // (a): iou matvec + gates -> h, c
            int nact = nn - gh * 4; if (nact > 4) nact = 4;
            float ai[4] = {0,0,0,0}, ao[4] = {0,0,0,0}, au[4] = {0,0,0,0};
            if (nact > 0) {
                for (int k = 0; k < MEM; k++) {
                    float wi = Wiouh[k * 768 + j];
                    float wo = Wiouh[k * 768 + 256 + j];
                    float wu = Wiouh[k * 768 + 512 + j];
                    #pragma unroll
                    for (int gg = 0; gg < 4; gg++) {
                        if (gg < nact) {
                            float hv = hsin[gh * 4 + gg][k];
                            ai[gg] = fmaf(wi, hv, ai[gg]);
                            ao[gg] = fmaf(wo, hv, ao[gg]);
                            au[gg] = fmaf(wu, hv, au[gg]);
                        }
                    }
                }
            }
            float creg[4];
            #pragma unroll
            for (int gg = 0; gg < 4; gg++) {
                if (gg < nact) {
                    int g = gh * 4 + gg;
                    int t = order[rs + g0 + g];
                    const float* io = ioux + t * 768;
                    float iv = ai[gg] + io[j]       + biouh[j];
                    float ov = ao[gg] + io[256 + j] + biouh[256 + j];
                    float uv = au[gg] + io[512 + j] + biouh[512 + j];
                    float isg = sigmf(iv), osg = sigmf(ov), ut = tanh_fast(uv);
                    float c = fmaf(isg, ut, fcin[g][j]);
                    float h = osg * tanh_fast(c);
                    creg[gg] = c;
                    hlds[g][j] = h;
                    H[t * MEM + j] = h;
                }
            }
            __syncthreads();

            // (b): forget gate matvec, write FC = f * c
            float fa[4] = {0,0,0,0};
            if (nact > 0) {
                for (int k = 0; k < MEM; k++) {
                    float w = Wfh[k * 256 + j];
                    #pragma unroll
                    for (int gg = 0; gg < 4; gg++) {
                        if (gg < nact)
                            fa[gg] = fmaf(w, hlds[gh * 4 + gg][k], fa[gg]);
                    }
                }
            }
            #pragma unroll
            for (int gg = 0; gg < 4; gg++) {
                if (gg < nact) {
                    int g = gh * 4 + gg;
                    int t = order[rs + g0 + g];
                    int p = par[t];
                    float f = sigmf(fa[gg] + bfh[j] + fx[p * MEM + j]);
                    FC[t * MEM + j] = f * creg[gg];
                }
            }
            __syncthreads();
        }
    }
}

// ---------------------------------------------------------------------------
// K3: attention (root rows only) + classifier head. 1 block, 256 threads.
// ---------------------------------------------------------------------------
__global__ __launch_bounds__(256) void k3_head(
        const float* __restrict__ Wattn, const float* __restrict__ battn,
        const float* __restrict__ Wwh,   const float* __restrict__ bwh,
        const float* __restrict__ Wwp,   const float* __restrict__ bwp,
        const float* __restrict__ ws, float* __restrict__ out) {
    const float* Hl = ws + H_OFF;
    const float* Hr = ws + H_OFF + 128 * 256;

    __shared__ float hlroot[MEM], hrroot[MEM];
    __shared__ float s[N_NODES], sc[N_NODES];
    __shared__ float beta[MEM], alpha[MEM];
    __shared__ float vl[MEM], vr[MEM];
    __shared__ float vec[2 * MEM];
    __shared__ float hid[HID];

    int tid = threadIdx.x;
    hlroot[tid] = Hl[127 * MEM + tid];
    hrroot[tid] = Hr[127 * MEM + tid];
    __syncthreads();

    if (tid < 128) {
        float a = 0.f;
        for (int k = 0; k < MEM; k++) a = fmaf(hlroot[k], Hr[tid * MEM + k], a);
        s[tid] = a;
    } else {
        int i = tid - 128; float a = 0.f;
        for (int k = 0; k < MEM; k++) a = fmaf(Hl[i * MEM + k], hrroot[k], a);
        sc[i] = a;
    }
    __syncthreads();

    if (tid < 2) {      // softmax over 128 (serial, tiny)
        float* v = tid ? sc : s;
        float m = -1e30f;
        for (int k = 0; k < 128; k++) m = fmaxf(m, v[k]);
        float su = 0.f;
        for (int k = 0; k < 128; k++) { float e = __expf(v[k] - m); v[k] = e; su += e; }
        float inv = 1.0f / su;
        for (int k = 0; k < 128; k++) v[k] *= inv;
    }
    __syncthreads();

    {   // beta = softmax(S[127,:]) @ Hr ; alpha = softmax(S[:,127]) @ Hl
        float b = 0.f, a2 = 0.f;
        for (int jj = 0; jj < 128; jj++) {
            b  = fmaf(s[jj],  Hr[jj * MEM + tid], b);
            a2 = fmaf(sc[jj], Hl[jj * MEM + tid], a2);
        }
        beta[tid] = b; alpha[tid] = a2;
    }
    __syncthreads();

    {   // vl = [hlroot, beta] @ Wattn + battn ; vr = [hrroot, alpha] @ Wattn + battn
        float a = 0.f, b = 0.f;
        for (int k = 0; k < MEM; k++) {
            float w = Wattn[k * MEM + tid];
            a = fmaf(hlroot[k], w, a);
            b = fmaf(hrroot[k], w, b);
        }
        for (int k = 0; k < MEM; k++) {
            float w = Wattn[(MEM + k) * MEM + tid];
            a = fmaf(beta[k],  w, a);
            b = fmaf(alpha[k], w, b);
        }
        vl[tid] = a + battn[tid];
        vr[tid] = b + battn[tid];
    }
    __syncthreads();

    vec[tid]       = vl[tid] * vr[tid];
    vec[MEM + tid] = fabsf(vl[tid] - vr[tid]);
    __syncthreads();

    if (tid < HID) {
        float a = 0.f;
        for (int k = 0; k < 2 * MEM; k++) a = fmaf(vec[k], Wwh[k * HID + tid], a);
        hid[tid] = sigmf(a + bwh[tid]);
    }
    __syncthreads();

    if (tid == 0) {
        float lg[NCLS];
        for (int c = 0; c < NCLS; c++) {
            float a = bwp[c];
            for (int k = 0; k < HID; k++) a = fmaf(hid[k], Wwp[k * NCLS + c], a);
            lg[c] = a;
        }
        float m = lg[0];
        for (int c = 1; c < NCLS; c++) m = fmaxf(m, lg[c]);
        float su = 0.f;
        for (int c = 0; c < NCLS; c++) su += __expf(lg[c] - m);
        float lse = logf(su);
        for (int c = 0; c < NCLS; c++) out[c] = lg[c] - m - lse;
    }
}

extern "C" void kernel_launch(void* const* d_in, const int* in_sizes, int n_in,
                              void* d_out, int out_size, void* d_ws, size_t ws_size,
                              hipStream_t stream) {
    const float* emb    = (const float*)d_in[0];
    const float* Wioux  = (const float*)d_in[1];
    const float* bioux  = (const float*)d_in[2];
    const float* Wiouh  = (const float*)d_in[3];
    const float* biouh  = (const float*)d_in[4];
    const float* Wfx    = (const float*)d_in[5];
    const float* bfx    = (const float*)d_in[6];
    const float* Wfh    = (const float*)d_in[7];
    const float* bfh    = (const float*)d_in[8];
    const float* Wattn  = (const float*)d_in[9];
    const float* battn  = (const float*)d_in[10];
    const float* Wwh    = (const float*)d_in[11];
    const float* bwh    = (const float*)d_in[12];
    const float* Wwp    = (const float*)d_in[13];
    const float* bwp    = (const float*)d_in[14];
    const int* linputs  = (const int*)d_in[15];
    const int* lparents = (const int*)d_in[16];
    const int* rinputs  = (const int*)d_in[17];
    const int* rparents = (const int*)d_in[18];
    float* ws  = (float*)d_ws;
    float* out = (float*)d_out;

    k1_prep<<<256, 256, 0, stream>>>(emb, Wioux, bioux, Wfx, bfx, linputs, rinputs, ws);
    k2_scan<<<2, 1024, 0, stream>>>(Wiouh, biouh, Wfh, bfh, lparents, rparents, ws);
    k3_head<<<1, 256, 0, stream>>>(Wattn, battn, Wwh, bwh, Wwp, bwp, ws, out);
}

// Round 2
// 250.149 us; speedup vs baseline: 6.6154x; 6.6154x over previous
//
#include <hip/hip_runtime.h>
#include <hip/hip_cooperative_groups.h>
#include <math.h>

namespace cg = cooperative_groups;

#define N_NODES 128
#define IN_DIM  512
#define MEM     256
#define HID     128
#define NCLS    5

// ws layout (float offsets)
#define IOUX_OFF 0                      // 2 * 128 * 768
#define FX_OFF   196608                 // 2 * 129 * 256 (row 128 = zero sentinel)
#define H_OFF    262656                 // 2 * 128 * 256
#define FC_OFF   328192                 // 2 * 128 * 256

#define NBT   16      // blocks per tree
#define SLICE 16      // j columns per block
#define PAD   264     // hsin/hv row pad (words), 16B aligned

__device__ __forceinline__ float sigmf(float x) {
    return 1.0f / (1.0f + __expf(-x));
}
__device__ __forceinline__ float tanh_fast(float x) {
    float e = __expf(2.0f * x);
    return 1.0f - 2.0f / (e + 1.0f);
}

// ---------------------------------------------------------------------------
// K1: 1024 blocks = (2 trees * 128 nodes) * 4 col-groups; 256 threads.
// cg 0..2: 256 cols of ioux; cg 3: 256 cols of fx.
// ---------------------------------------------------------------------------
__global__ __launch_bounds__(256) void k1_prep(
        const float* __restrict__ emb,
        const float* __restrict__ Wioux, const float* __restrict__ bioux,
        const float* __restrict__ Wfx,   const float* __restrict__ bfx,
        const int* __restrict__ linputs, const int* __restrict__ rinputs,
        float* __restrict__ ws) {
    int bid = blockIdx.x;
    int tn = bid >> 2;          // tree*128 + node
    int cg = bid & 3;
    int tree = tn >> 7;
    int node = tn & 127;
    const int* inp = tree ? rinputs : linputs;
    int tok = inp[node];

    __shared__ float X[IN_DIM];
    int tid = threadIdx.x;
    {
        float2 v = ((const float2*)(emb + (size_t)tok * IN_DIM))[tid];
        X[tid * 2] = v.x; X[tid * 2 + 1] = v.y;
    }
    __syncthreads();

    float acc = 0.f;
    if (cg < 3) {
        int col = cg * 256 + tid;       // 0..767
        #pragma unroll 8
        for (int k = 0; k < IN_DIM; k++)
            acc = fmaf(X[k], Wioux[k * 768 + col], acc);
        ws[IOUX_OFF + (size_t)tn * 768 + col] = acc + bioux[col];
    } else {
        #pragma unroll 8
        for (int k = 0; k < IN_DIM; k++)
            acc = fmaf(X[k], Wfx[k * 256 + tid], acc);
        ws[FX_OFF + ((size_t)tree * 129 + node) * 256 + tid] = acc + bfx[tid];
        if (node == 0)      // zero the sentinel fx row (parent == 128)
            ws[FX_OFF + ((size_t)tree * 129 + 128) * 256 + tid] = 0.f;
    }
}

// ---------------------------------------------------------------------------
// K2: cooperative level-order TreeLSTM. 32 blocks (16/tree) x 256 threads.
// Block owns 16 j-columns; weights live in registers (64 f32/thread).
// One grid.sync() per level (between iou-phase and f-phase).
// ---------------------------------------------------------------------------
__device__ int relax_levels(const int* __restrict__ parents, int* par, int* rnd,
                            int* changed, int tid) {
    if (tid < N_NODES) { par[tid] = parents[tid]; rnd[tid] = 0; }
    __syncthreads();
    for (;;) {
        if (tid == 0) *changed = 0;
        __syncthreads();
        if (tid < N_NODES) {
            int p = par[tid];
            if (p < N_NODES) {
                int v = rnd[tid] + 1;
                if (atomicMax(&rnd[p], v) < v) *changed = 1;
            }
        }
        __syncthreads();
        int done = (*changed == 0);
        __syncthreads();
        if (done) break;
    }
    return rnd[N_NODES - 1] + 1;   // root (N-1) carries the max level
}

__global__ __launch_bounds__(256, 1) void k2_coop(
        const float* __restrict__ Wiouh, const float* __restrict__ biouh,
        const float* __restrict__ Wfh,   const float* __restrict__ bfh,
        const int* __restrict__ lparents, const int* __restrict__ rparents,
        float* __restrict__ ws) {
    cg::grid_group grid = cg::this_grid();

    int bid = blockIdx.x;
    int tree = bid >> 4;
    int slice = (bid & 15) * SLICE;
    const int* parents  = tree ? rparents : lparents;
    const int* oparents = tree ? lparents : rparents;
    const float* ioux = ws + IOUX_OFF + (size_t)tree * 128 * 768;
    const float* fx   = ws + FX_OFF   + (size_t)tree * 129 * 256;
    float* H  = ws + H_OFF  + (size_t)tree * 128 * 256;
    float* FC = ws + FC_OFF + (size_t)tree * 128 * 256;

    __shared__ float hsin[8][PAD];
    __shared__ float hv[8][PAD];
    __shared__ float red[16][8][3][17];
    __shared__ float fcin[8][16];
    __shared__ float cc[128][16];
    __shared__ int par[N_NODES], rnd[N_NODES], order[N_NODES];
    __shared__ int rstart[N_NODES + 1], kids[N_NODES], kstart[N_NODES + 1];
    __shared__ int cnt[N_NODES + 1];
    __shared__ int changed;

    int tid = threadIdx.x;
    int j  = tid & 15;
    int kg = tid >> 4;            // 16 k-groups of 16
    int jcol = slice + j;

    // ---- weights into registers (held for whole kernel) ----
    float Wi[16], Wo[16], Wu[16], Wf[16];
    #pragma unroll
    for (int kk = 0; kk < 16; kk++) {
        int k = kg * 16 + kk;
        Wi[kk] = Wiouh[k * 768 + jcol];
        Wo[kk] = Wiouh[k * 768 + 256 + jcol];
        Wu[kk] = Wiouh[k * 768 + 512 + jcol];
        Wf[kk] = Wfh[k * 256 + jcol];
    }
    // bias prefetch for epilogue threads (tid<128 uses same j mapping)
    float bio0 = 0.f, bio1 = 0.f, bio2 = 0.f, bfr = 0.f;
    if (tid < 128) {
        bio0 = biouh[jcol];
        bio1 = biouh[256 + jcol];
        bio2 = biouh[512 + jcol];
        bfr  = bfh[jcol];
    }

    // ---- prologue: level structure ----
    int nr_other = relax_levels(oparents, par, rnd, &changed, tid);
    int nr       = relax_levels(parents,  par, rnd, &changed, tid);
    int NR = nr > nr_other ? nr : nr_other;

    // counting sort nodes by level (stable)
    if (tid <= N_NODES) cnt[tid] = 0;
    __syncthreads();
    if (tid < N_NODES) atomicAdd(&cnt[rnd[tid]], 1);
    __syncthreads();
    if (tid == 0) {
        int acc = 0;
        for (int rr = 0; rr < N_NODES; rr++) { rstart[rr] = acc; acc += cnt[rr]; }
        rstart[N_NODES] = acc;
    }
    __syncthreads();
    if (tid < N_NODES) {
        int rr = rnd[tid], rank = 0;
        for (int t2 = 0; t2 < tid; t2++) rank += (rnd[t2] == rr) ? 1 : 0;
        order[rstart[rr] + rank] = tid;
    }
    // children adjacency (stable)
    if (tid <= N_NODES) cnt[tid] = 0;
    __syncthreads();
    if (tid < N_NODES) atomicAdd(&cnt[par[tid]], 1);
    __syncthreads();
    if (tid == 0) {
        int acc = 0;
        for (int t = 0; t <= N_NODES; t++) { kstart[t] = acc; acc += cnt[t]; }
    }
    __syncthreads();
    if (tid < N_NODES) {
        int p = par[tid], rank = 0;
        for (int t2 = 0; t2 < tid; t2++) rank += (par[t2] == p) ? 1 : 0;
        kids[kstart[p] + rank] = tid;
    }
    __syncthreads();

    // ---- main level loop ----
    for (int r = 0; r < NR; r++) {
        int rs = 0, re = 0;
        if (r < nr) { rs = rstart[r]; re = rstart[r + 1]; }

        // ======== phase A: gather + iou matvec + gates -> H, c ========
        for (int base = rs; base < re; base += 8) {
            int nn = re - base; if (nn > 8) nn = 8;
            {   // gather child h-sums (full k range)
                int n = tid >> 5, kc = tid & 31;
                float4 a0 = make_float4(0.f, 0.f, 0.f, 0.f), a1 = a0;
                if (n < nn) {
                    int t = order[base + n];
                    for (int ci = kstart[t]; ci < kstart[t + 1]; ci++) {
                        int ch = kids[ci];
                        const float4* hp = (const float4*)(H + ch * 256 + kc * 8);
                        float4 x0 = hp[0], x1 = hp[1];
                        a0.x += x0.x; a0.y += x0.y; a0.z += x0.z; a0.w += x0.w;
                        a1.x += x1.x; a1.y += x1.y; a1.z += x1.z; a1.w += x1.w;
                    }
                }
                *(float4*)&hsin[n][kc * 8]     = a0;
                *(float4*)&hsin[n][kc * 8 + 4] = a1;
            }
            if (tid < 128) {   // gather fc-sums (own j-slice only)
                int n2 = tid >> 4, j2 = tid & 15;
                float fc = 0.f;
                if (n2 < nn) {
                    int t = order[base + n2];
                    for (int ci = kstart[t]; ci < kstart[t + 1]; ci++)
                        fc += FC[kids[ci] * 256 + slice + j2];
                }
                fcin[n2][j2] = fc;
            }
            __syncthreads();

            // register-weight matvec: 8 nodes x 3 gates over own 16-k range
            float ai[8], ao[8], au[8];
            #pragma unroll
            for (int n = 0; n < 8; n++) { ai[n] = 0.f; ao[n] = 0.f; au[n] = 0.f; }
            #pragma unroll
            for (int q = 0; q < 4; q++) {
                #pragma unroll
                for (int n = 0; n < 8; n++) {
                    float4 v = *(const float4*)&hsin[n][kg * 16 + q * 4];
                    ai[n] = fmaf(Wi[q*4+0], v.x, ai[n]);
                    ai[n] = fmaf(Wi[q*4+1], v.y, ai[n]);
                    ai[n] = fmaf(Wi[q*4+2], v.z, ai[n]);
                    ai[n] = fmaf(Wi[q*4+3], v.w, ai[n]);
                    ao[n] = fmaf(Wo[q*4+0], v.x, ao[n]);
                    ao[n] = fmaf(Wo[q*4+1], v.y, ao[n]);
                    ao[n] = fmaf(Wo[q*4+2], v.z, ao[n]);
                    ao[n] = fmaf(Wo[q*4+3], v.w, ao[n]);
                    au[n] = fmaf(Wu[q*4+0], v.x, au[n]);
                    au[n] = fmaf(Wu[q*4+1], v.y, au[n]);
                    au[n] = fmaf(Wu[q*4+2], v.z, au[n]);
                    au[n] = fmaf(Wu[q*4+3], v.w, au[n]);
                }
            }
            #pragma unroll
            for (int n = 0; n < 8; n++) {
                red[kg][n][0][j] = ai[n];
                red[kg][n][1][j] = ao[n];
                red[kg][n][2][j] = au[n];
            }
            __syncthreads();

            if (tid < 128) {   // reduce over 16 k-groups + gates
                int n = tid >> 4, jj = tid & 15;
                if (n < nn) {
                    float si = 0.f, so = 0.f, su = 0.f;
                    #pragma unroll
                    for (int g = 0; g < 16; g++) {
                        si += red[g][n][0][jj];
                        so += red[g][n][1][jj];
                        su += red[g][n][2][jj];
                    }
                    int t = order[base + n];
                    const float* io = ioux + t * 768;
                    float iv = si + io[jcol]       + bio0;
                    float ov = so + io[256 + jcol] + bio1;
                    float uv = su + io[512 + jcol] + bio2;
                    float c = fmaf(sigmf(iv), tanh_fast(uv), fcin[n][jj]);
                    float h = sigmf(ov) * tanh_fast(c);
                    H[t * 256 + jcol] = h;
                    cc[t][jj] = c;
                }
            }
            __syncthreads();
        }

        grid.sync();   // level-r H fully written by all column blocks

        // ======== phase B: forget-gate matvec -> FC ========
        for (int base = rs; base < re; base += 8) {
            int nn = re - base; if (nn > 8) nn = 8;
            {   // load full h rows of this batch into LDS
                int n = tid >> 5, kc = tid & 31;
                float4 x0 = make_float4(0.f, 0.f, 0.f, 0.f), x1 = x0;
                if (n < nn) {
                    int t = order[base + n];
                    const float4* hp = (const float4*)(H + t * 256 + kc * 8);
                    x0 = hp[0]; x1 = hp[1];
                }
                *(float4*)&hv[n][kc * 8]     = x0;
                *(float4*)&hv[n][kc * 8 + 4] = x1;
            }
            __syncthreads();

            float af[8];
            #pragma unroll
            for (int n = 0; n < 8; n++) af[n] = 0.f;
            #pragma unroll
            for (int q = 0; q < 4; q++) {
                #pragma unroll
                for (int n = 0; n < 8; n++) {
                    float4 v = *(const float4*)&hv[n][kg * 16 + q * 4];
                    af[n] = fmaf(Wf[q*4+0], v.x, af[n]);
                    af[n] = fmaf(Wf[q*4+1], v.y, af[n]);
                    af[n] = fmaf(Wf[q*4+2], v.z, af[n]);
                    af[n] = fmaf(Wf[q*4+3], v.w, af[n]);
                }
            }
            #pragma unroll
            for (int n = 0; n < 8; n++) red[kg][n][0][j] = af[n];
            __syncthreads();

            if (tid < 128) {
                int n = tid >> 4, jj = tid & 15;
                if (n < nn) {
                    float sf = 0.f;
                    #pragma unroll
                    for (int g = 0; g < 16; g++) sf += red[g][n][0][jj];
                    int t = order[base + n];
                    int p = par[t];
                    float f = sigmf(sf + bfr + fx[p * 256 + jcol]);
                    FC[t * 256 + jcol] = f * cc[t][jj];
                }
            }
            __syncthreads();
        }
    }
}

// ---------------------------------------------------------------------------
// K3: attention (root rows only) + classifier head. 1 block, 256 threads.
// ---------------------------------------------------------------------------
__global__ __launch_bounds__(256) void k3_head(
        const float* __restrict__ Wattn, const float* __restrict__ battn,
        const float* __restrict__ Wwh,   const float* __restrict__ bwh,
        const float* __restrict__ Wwp,   const float* __restrict__ bwp,
        const float* __restrict__ ws, float* __restrict__ out) {
    const float* Hl = ws + H_OFF;
    const float* Hr = ws + H_OFF + 128 * 256;

    __shared__ float hlroot[MEM], hrroot[MEM];
    __shared__ float s[N_NODES], sc[N_NODES];
    __shared__ float beta[MEM], alpha[MEM];
    __shared__ float vl[MEM], vr[MEM];
    __shared__ float vec[2 * MEM];
    __shared__ float hid[HID];

    int tid = threadIdx.x;
    hlroot[tid] = Hl[127 * MEM + tid];
    hrroot[tid] = Hr[127 * MEM + tid];
    __syncthreads();

    if (tid < 128) {
        float a = 0.f;
        for (int k = 0; k < MEM; k++) a = fmaf(hlroot[k], Hr[tid * MEM + k], a);
        s[tid] = a;
    } else {
        int i = tid - 128; float a = 0.f;
        for (int k = 0; k < MEM; k++) a = fmaf(Hl[i * MEM + k], hrroot[k], a);
        sc[i] = a;
    }
    __syncthreads();

    if (tid < 2) {
        float* v = tid ? sc : s;
        float m = -1e30f;
        for (int k = 0; k < 128; k++) m = fmaxf(m, v[k]);
        float su = 0.f;
        for (int k = 0; k < 128; k++) { float e = __expf(v[k] - m); v[k] = e; su += e; }
        float inv = 1.0f / su;
        for (int k = 0; k < 128; k++) v[k] *= inv;
    }
    __syncthreads();

    {
        float b = 0.f, a2 = 0.f;
        for (int jj = 0; jj < 128; jj++) {
            b  = fmaf(s[jj],  Hr[jj * MEM + tid], b);
            a2 = fmaf(sc[jj], Hl[jj * MEM + tid], a2);
        }
        beta[tid] = b; alpha[tid] = a2;
    }
    __syncthreads();

    {
        float a = 0.f, b = 0.f;
        for (int k = 0; k < MEM; k++) {
            float w = Wattn[k * MEM + tid];
            a = fmaf(hlroot[k], w, a);
            b = fmaf(hrroot[k], w, b);
        }
        for (int k = 0; k < MEM; k++) {
            float w = Wattn[(MEM + k) * MEM + tid];
            a = fmaf(beta[k],  w, a);
            b = fmaf(alpha[k], w, b);
        }
        vl[tid] = a + battn[tid];
        vr[tid] = b + battn[tid];
    }
    __syncthreads();

    vec[tid]       = vl[tid] * vr[tid];
    vec[MEM + tid] = fabsf(vl[tid] - vr[tid]);
    __syncthreads();

    if (tid < HID) {
        float a = 0.f;
        for (int k = 0; k < 2 * MEM; k++) a = fmaf(vec[k], Wwh[k * HID + tid], a);
        hid[tid] = sigmf(a + bwh[tid]);
    }
    __syncthreads();

    if (tid == 0) {
        float lg[NCLS];
        for (int c = 0; c < NCLS; c++) {
            float a = bwp[c];
            for (int k = 0; k < HID; k++) a = fmaf(hid[k], Wwp[k * NCLS + c], a);
            lg[c] = a;
        }
        float m = lg[0];
        for (int c = 1; c < NCLS; c++) m = fmaxf(m, lg[c]);
        float su = 0.f;
        for (int c = 0; c < NCLS; c++) su += __expf(lg[c] - m);
        float lse = logf(su);
        for (int c = 0; c < NCLS; c++) out[c] = lg[c] - m - lse;
    }
}

extern "C" void kernel_launch(void* const* d_in, const int* in_sizes, int n_in,
                              void* d_out, int out_size, void* d_ws, size_t ws_size,
                              hipStream_t stream) {
    const float* emb    = (const float*)d_in[0];
    const float* Wioux  = (const float*)d_in[1];
    const float* bioux  = (const float*)d_in[2];
    const float* Wiouh  = (const float*)d_in[3];
    const float* biouh  = (const float*)d_in[4];
    const float* Wfx    = (const float*)d_in[5];
    const float* bfx    = (const float*)d_in[6];
    const float* Wfh    = (const float*)d_in[7];
    const float* bfh    = (const float*)d_in[8];
    const float* Wattn  = (const float*)d_in[9];
    const float* battn  = (const float*)d_in[10];
    const float* Wwh    = (const float*)d_in[11];
    const float* bwh    = (const float*)d_in[12];
    const float* Wwp    = (const float*)d_in[13];
    const float* bwp    = (const float*)d_in[14];
    const int* linputs  = (const int*)d_in[15];
    const int* lparents = (const int*)d_in[16];
    const int* rinputs  = (const int*)d_in[17];
    const int* rparents = (const int*)d_in[18];
    float* ws  = (float*)d_ws;
    float* out = (float*)d_out;

    k1_prep<<<1024, 256, 0, stream>>>(emb, Wioux, bioux, Wfx, bfx,
                                      linputs, rinputs, ws);

    void* args[] = {
        (void*)&Wiouh, (void*)&biouh, (void*)&Wfh, (void*)&bfh,
        (void*)&lparents, (void*)&rparents, (void*)&ws
    };
    hipLaunchCooperativeKernel((void*)k2_coop, dim3(32), dim3(256),
                               args, 0, stream);

    k3_head<<<1, 256, 0, stream>>>(Wattn, battn, Wwh, bwh, Wwp, bwp, ws, out);
}